// Round 5
// baseline (1042.963 us; speedup 1.0000x reference)
//
#include <hip/hip_runtime.h>

#define IN_CH 128
#define HID 64
#define OUT_CH 16

#define G_SH 7
#define G_SZ 128          // dst nodes per bucket
#define NBK_MAX 800       // max buckets (n <= 102400)
#define CHUNK 4096        // edges per bucketing block

// ---------------- degree / norm ----------------

__global__ void k_zero_int(int* __restrict__ p, int n) {
    int i = blockIdx.x * blockDim.x + threadIdx.x;
    if (i < n) p[i] = 0;
}

__global__ void k_count(const int* __restrict__ ei, int* __restrict__ counts, int E) {
    int e = blockIdx.x * blockDim.x + threadIdx.x;
    if (e < E) atomicAdd(&counts[ei[E + e]], 1);  // row 1 = dst
}

__global__ void k_dinv(const int* __restrict__ counts, float* __restrict__ dinv, int n) {
    int i = blockIdx.x * blockDim.x + threadIdx.x;
    if (i < n) dinv[i] = rsqrtf((float)(counts[i] + 1));  // +1 = self-loop
}

// bcnt[b] = sum of counts over bucket's 128-node range; one 128-thread block per bucket
__global__ __launch_bounds__(128) void k_bucket_cnt(const int* __restrict__ counts,
                                                    int* __restrict__ bcnt, int n) {
    __shared__ int s[128];
    int d = (blockIdx.x << G_SH) + threadIdx.x;
    s[threadIdx.x] = (d < n) ? counts[d] : 0;
    __syncthreads();
    for (int off = 64; off > 0; off >>= 1) {
        if (threadIdx.x < off) s[threadIdx.x] += s[threadIdx.x + off];
        __syncthreads();
    }
    if (threadIdx.x == 0) bcnt[blockIdx.x] = s[0];
}

// single-block exclusive scan of bucket counts -> boff (nb+1) and bcursor copy
__global__ __launch_bounds__(256) void k_scan_small(const int* __restrict__ bcnt,
                                                    int* __restrict__ boff,
                                                    int* __restrict__ bcursor, int nb) {
    __shared__ int s[256];
    __shared__ int carry;
    if (threadIdx.x == 0) carry = 0;
    __syncthreads();
    for (int base = 0; base < nb; base += 256) {
        int i = base + threadIdx.x;
        int v = (i < nb) ? bcnt[i] : 0;
        s[threadIdx.x] = v;
        __syncthreads();
        for (int off = 1; off < 256; off <<= 1) {
            int t = (threadIdx.x >= off) ? s[threadIdx.x - off] : 0;
            __syncthreads();
            s[threadIdx.x] += t;
            __syncthreads();
        }
        if (i < nb) {
            int ex = carry + s[threadIdx.x] - v;
            boff[i] = ex;
            bcursor[i] = ex;
        }
        __syncthreads();
        if (threadIdx.x == 255) carry += s[255];
        __syncthreads();
    }
    if (threadIdx.x == 0) boff[nb] = carry;
}

// ---------------- edge bucketing (coarse sort by dst>>7) ----------------
// packed edge word: (d_local << 17) | src   (src < 2^17, d_local < 128)
__global__ __launch_bounds__(256) void k_bucket(const int* __restrict__ ei,
                                                int* __restrict__ bcursor,
                                                int* __restrict__ packed, int E, int nb) {
    __shared__ int hcnt[NBK_MAX];
    __shared__ int hoff[NBK_MAX];   // local exclusive offsets
    __shared__ int hbase[NBK_MAX];  // global base per bucket
    __shared__ int hcur[NBK_MAX];   // local fill cursor
    __shared__ int stage[CHUNK];
    __shared__ unsigned short sbk[CHUNK];
    __shared__ int scan_s[256];
    __shared__ int sh_carry;

    int tid = threadIdx.x;
    int base = blockIdx.x * CHUNK;
    int cnt = E - base;
    if (cnt > CHUNK) cnt = CHUNK;
    for (int t = tid; t < nb; t += 256) { hcnt[t] = 0; hcur[t] = 0; }
    if (tid == 0) sh_carry = 0;
    __syncthreads();

    int ms[CHUNK / 256], mb[CHUNK / 256], ml[CHUNK / 256];
#pragma unroll
    for (int k = 0; k < CHUNK / 256; ++k) {
        int idx = base + k * 256 + tid;
        int s = 0, b = -1, dl = 0;
        if (idx < E) {
            s = ei[idx];
            int d = ei[E + idx];
            b = d >> G_SH;
            dl = d & (G_SZ - 1);
            atomicAdd(&hcnt[b], 1);
        }
        ms[k] = s; mb[k] = b; ml[k] = dl;
    }
    __syncthreads();

    // exclusive scan of hcnt -> hoff
    for (int s0 = 0; s0 < nb; s0 += 256) {
        int i = s0 + tid;
        int v = (i < nb) ? hcnt[i] : 0;
        scan_s[tid] = v;
        __syncthreads();
        for (int off = 1; off < 256; off <<= 1) {
            int t = (tid >= off) ? scan_s[tid - off] : 0;
            __syncthreads();
            scan_s[tid] += t;
            __syncthreads();
        }
        if (i < nb) hoff[i] = sh_carry + scan_s[tid] - v;
        __syncthreads();
        if (tid == 255) sh_carry += scan_s[255];
        __syncthreads();
    }

    // reserve global space per bucket
    for (int t = tid; t < nb; t += 256)
        if (hcnt[t] > 0) hbase[t] = atomicAdd(&bcursor[t], hcnt[t]);
    __syncthreads();

    // LDS scatter into bucket-ordered staging
#pragma unroll
    for (int k = 0; k < CHUNK / 256; ++k) {
        int b = mb[k];
        if (b >= 0) {
            int slot = hoff[b] + atomicAdd(&hcur[b], 1);
            stage[slot] = (ml[k] << 17) | ms[k];
            sbk[slot] = (unsigned short)b;
        }
    }
    __syncthreads();

    // coalesced run write-out
    for (int i = tid; i < cnt; i += 256) {
        int b = sbk[i];
        packed[hbase[b] + (i - hoff[b])] = stage[i];
    }
}

// ---------------- layer 1 ----------------

// xlp = dinv * (x @ W1); 8 nodes/block, 2 nodes/thread
__global__ __launch_bounds__(256) void k_gemm1(const float* __restrict__ x,
                                               const float* __restrict__ W,
                                               const float* __restrict__ dinv,
                                               float* __restrict__ xlp, int n) {
    __shared__ float sx[8][IN_CH];
    int node0 = blockIdx.x * 8;
    int tid = threadIdx.x;
    {
        int r = tid >> 5, k4 = tid & 31;
        int node = node0 + r;
        float4 v = (node < n) ? ((const float4*)(x + (size_t)node * IN_CH))[k4]
                              : make_float4(0.f, 0.f, 0.f, 0.f);
        ((float4*)sx[r])[k4] = v;
    }
    __syncthreads();
    int r = tid >> 6, j = tid & 63;
    float acc0 = 0.f, acc1 = 0.f;
#pragma unroll 8
    for (int k = 0; k < IN_CH; ++k) {
        float w = W[k * HID + j];
        acc0 += sx[r][k] * w;
        acc1 += sx[r + 4][k] * w;
    }
    int nodeA = node0 + r, nodeB = node0 + r + 4;
    if (nodeA < n) xlp[(size_t)nodeA * HID + j] = dinv[nodeA] * acc0;
    if (nodeB < n) xlp[(size_t)nodeB * HID + j] = dinv[nodeB] * acc1;
}

// bucketed aggregate, LDS accumulator, fused self-loop+bias+relu
__global__ __launch_bounds__(256) void k_agg1(const int* __restrict__ boff,
                                              const int* __restrict__ packed,
                                              const float* __restrict__ dinv,
                                              const float* __restrict__ xlp,
                                              const float* __restrict__ bias,
                                              float* __restrict__ h, int n) {
    __shared__ __align__(16) float acc[G_SZ][HID];  // 32 KB
    int tid = threadIdx.x;
    for (int i = tid; i < G_SZ * HID / 4; i += 256)
        ((float4*)&acc[0][0])[i] = make_float4(0.f, 0.f, 0.f, 0.f);
    __syncthreads();

    int bkt = blockIdx.x;
    int j0 = boff[bkt], j1 = boff[bkt + 1];
    int w = tid >> 6, c = tid & 63;
    for (int j = j0 + w * 4; j < j1; j += 16) {
        int e = j1 - j; e = e > 4 ? 4 : e;
        int p[4]; float v[4]; int dl[4];
#pragma unroll
        for (int k = 0; k < 4; ++k) if (k < e) p[k] = packed[j + k];
#pragma unroll
        for (int k = 0; k < 4; ++k) if (k < e) {
            int s = p[k] & 0x1FFFF;
            dl[k] = p[k] >> 17;
            v[k] = xlp[(size_t)s * HID + c];
        }
#pragma unroll
        for (int k = 0; k < 4; ++k) if (k < e)
            atomicAdd(&acc[dl[k]][c], v[k]);  // ds_add_f32, no dep chain
    }
    __syncthreads();

    int d0 = bkt << G_SH;
    for (int i = tid; i < G_SZ * HID; i += 256) {
        int dl = i >> 6, cc = i & 63;
        int d = d0 + dl;
        if (d < n) {
            float dd = dinv[d];
            float val = dd * (acc[dl][cc] + xlp[(size_t)d * HID + cc]) + bias[cc];
            h[(size_t)d * HID + cc] = fmaxf(val, 0.f);
        }
    }
}

// ---------------- layer 2 ----------------

// hlp = dinv * (h @ W2); 16 nodes/block
__global__ __launch_bounds__(256) void k_gemm2(const float* __restrict__ h,
                                               const float* __restrict__ W,
                                               const float* __restrict__ dinv,
                                               float* __restrict__ hlp, int n) {
    __shared__ float sW[HID * OUT_CH];
    __shared__ float sh[16][HID];
    int tid = threadIdx.x;
    for (int t = tid; t < HID * OUT_CH; t += 256) sW[t] = W[t];
    int node0 = blockIdx.x * 16;
    for (int t = tid; t < 16 * HID / 4; t += 256) {
        int r = t >> 4, k4 = t & 15;
        int node = node0 + r;
        float4 v = (node < n) ? ((const float4*)(h + (size_t)node * HID))[k4]
                              : make_float4(0.f, 0.f, 0.f, 0.f);
        ((float4*)sh[r])[k4] = v;
    }
    __syncthreads();
    int r = tid >> 4, j = tid & 15;
    int node = node0 + r;
    if (node >= n) return;
    float acc = 0.f;
#pragma unroll
    for (int k = 0; k < HID; ++k)
        acc += sh[r][k] * sW[k * OUT_CH + j];
    hlp[(size_t)node * OUT_CH + j] = dinv[node] * acc;
}

// bucketed aggregate for layer 2, fused self-loop+bias
__global__ __launch_bounds__(256) void k_agg2(const int* __restrict__ boff,
                                              const int* __restrict__ packed,
                                              const float* __restrict__ dinv,
                                              const float* __restrict__ hlp,
                                              const float* __restrict__ bias,
                                              float* __restrict__ out, int n) {
    __shared__ __align__(16) float acc[G_SZ][OUT_CH];  // 8 KB
    int tid = threadIdx.x;
    for (int i = tid; i < G_SZ * OUT_CH / 4; i += 256)
        ((float4*)&acc[0][0])[i] = make_float4(0.f, 0.f, 0.f, 0.f);
    __syncthreads();

    int bkt = blockIdx.x;
    int j0 = boff[bkt], j1 = boff[bkt + 1];
    int g = tid >> 4, c = tid & 15;  // 16 groups of 16 lanes
    for (int j = j0 + g * 4; j < j1; j += 64) {
        int e = j1 - j; e = e > 4 ? 4 : e;
        int p[4]; float v[4]; int dl[4];
#pragma unroll
        for (int k = 0; k < 4; ++k) if (k < e) p[k] = packed[j + k];
#pragma unroll
        for (int k = 0; k < 4; ++k) if (k < e) {
            int s = p[k] & 0x1FFFF;
            dl[k] = p[k] >> 17;
            v[k] = hlp[(size_t)s * OUT_CH + c];
        }
#pragma unroll
        for (int k = 0; k < 4; ++k) if (k < e)
            atomicAdd(&acc[dl[k]][c], v[k]);
    }
    __syncthreads();

    int d0 = bkt << G_SH;
    for (int i = tid; i < G_SZ * OUT_CH; i += 256) {
        int dl = i >> 4, cc = i & 15;
        int d = d0 + dl;
        if (d < n) {
            float dd = dinv[d];
            out[(size_t)d * OUT_CH + cc] =
                dd * (acc[dl][cc] + hlp[(size_t)d * OUT_CH + cc]) + bias[cc];
        }
    }
}

extern "C" void kernel_launch(void* const* d_in, const int* in_sizes, int n_in,
                              void* d_out, int out_size, void* d_ws, size_t ws_size,
                              hipStream_t stream) {
    const float* x  = (const float*)d_in[0];
    const int* ei   = (const int*)d_in[1];   // int32 from harness
    const float* W1 = (const float*)d_in[2];
    const float* b1 = (const float*)d_in[3];
    const float* W2 = (const float*)d_in[4];
    const float* b2 = (const float*)d_in[5];
    float* out = (float*)d_out;

    const int n = in_sizes[0] / IN_CH;   // 100000
    const int E = in_sizes[1] / 2;       // 1600000
    const int nb = (n + G_SZ - 1) >> G_SH;  // 782 buckets (<= NBK_MAX)

    // workspace layout (int units, all starts 16B-aligned); total ~58.4 MB
    int* counts  = (int*)d_ws;           // n
    int* bcnt    = counts + 100000;      // 1024
    int* boff    = bcnt + 1024;          // 1032 (nb+1 used)
    int* bcursor = boff + 1032;          // 1024
    int* packed  = bcursor + 1024;       // E
    float* dinv  = (float*)(packed + E); // n
    float* xlp   = dinv + 100000;        // n*64; aliased as hlp later
    float* h     = xlp + (size_t)n * HID;// n*64
    float* hlp   = xlp;                  // xlp dead after k_agg1

    // degree, dinv, bucket offsets
    k_zero_int<<<(n + 255) / 256, 256, 0, stream>>>(counts, n);
    k_count<<<(E + 255) / 256, 256, 0, stream>>>(ei, counts, E);
    k_dinv<<<(n + 255) / 256, 256, 0, stream>>>(counts, dinv, n);
    k_bucket_cnt<<<nb, 128, 0, stream>>>(counts, bcnt, n);
    k_scan_small<<<1, 256, 0, stream>>>(bcnt, boff, bcursor, nb);

    // coarse bucket sort of edges
    k_bucket<<<(E + CHUNK - 1) / CHUNK, 256, 0, stream>>>(ei, bcursor, packed, E, nb);

    // layer 1
    k_gemm1<<<(n + 7) / 8, 256, 0, stream>>>(x, W1, dinv, xlp, n);
    k_agg1<<<nb, 256, 0, stream>>>(boff, packed, dinv, xlp, b1, h, n);

    // layer 2
    k_gemm2<<<(n + 15) / 16, 256, 0, stream>>>(h, W2, dinv, hlp, n);
    k_agg2<<<nb, 256, 0, stream>>>(boff, packed, dinv, hlp, b2, out, n);
}

// Round 6
// 285.627 us; speedup vs baseline: 3.6515x; 3.6515x over previous
//
#include <hip/hip_runtime.h>

#define IN_CH 128
#define HID 64
#define OUT_CH 16

#define G_SH 7
#define G_SZ 128          // dst nodes per bucket
#define NBK_MAX 800       // max buckets (n <= 102400)
#define CHUNK 4096        // edges per bucketing block
#define SORT_CAP 4096     // max edges per bucket (mean 2048, std ~45)

// ---------------- degree ----------------

__global__ void k_zero_int(int* __restrict__ p, int n) {
    int i = blockIdx.x * blockDim.x + threadIdx.x;
    if (i < n) p[i] = 0;
}

__global__ void k_count(const int* __restrict__ ei, int* __restrict__ counts, int E) {
    int e = blockIdx.x * blockDim.x + threadIdx.x;
    if (e < E) atomicAdd(&counts[ei[E + e]], 1);  // row 1 = dst
}

// phase 1: per-block exclusive scan counts -> rowptr (counts preserved) + fused dinv
__global__ __launch_bounds__(256) void k_scan_local(const int* __restrict__ counts,
                                                    int* __restrict__ rowptr,
                                                    int* __restrict__ blk_sum,
                                                    float* __restrict__ dinv, int n) {
    __shared__ int s[256];
    int i = blockIdx.x * 256 + threadIdx.x;
    int v = (i < n) ? counts[i] : 0;
    if (i < n) dinv[i] = rsqrtf((float)(v + 1));  // +1 = self-loop
    s[threadIdx.x] = v;
    __syncthreads();
    for (int off = 1; off < 256; off <<= 1) {
        int t = (threadIdx.x >= off) ? s[threadIdx.x - off] : 0;
        __syncthreads();
        s[threadIdx.x] += t;
        __syncthreads();
    }
    if (i < n) rowptr[i] = s[threadIdx.x] - v;  // exclusive within block
    if (threadIdx.x == 255) blk_sum[blockIdx.x] = s[255];
}

// phase 2: single-block exclusive scan of block sums
__global__ __launch_bounds__(256) void k_scan_blocks(int* __restrict__ blk, int nblk) {
    __shared__ int s[256];
    __shared__ int sh_carry;
    if (threadIdx.x == 0) sh_carry = 0;
    __syncthreads();
    for (int base = 0; base < nblk; base += 256) {
        int carry = sh_carry;
        int i = base + threadIdx.x;
        int v = (i < nblk) ? blk[i] : 0;
        s[threadIdx.x] = v;
        __syncthreads();
        for (int off = 1; off < 256; off <<= 1) {
            int t = (threadIdx.x >= off) ? s[threadIdx.x - off] : 0;
            __syncthreads();
            s[threadIdx.x] += t;
            __syncthreads();
        }
        if (i < nblk) blk[i] = carry + s[threadIdx.x] - v;
        if (threadIdx.x == 255) sh_carry = carry + s[255];
        __syncthreads();
    }
}

// phase 3: add block offsets; init per-bucket cursor = rowptr[b<<7]
__global__ void k_scan_add(int* __restrict__ rowptr, const int* __restrict__ blk,
                           int* __restrict__ bcursor, int n) {
    int i = blockIdx.x * blockDim.x + threadIdx.x;
    if (i < n) {
        int r = rowptr[i] + blk[blockIdx.x];
        rowptr[i] = r;
        if ((i & (G_SZ - 1)) == 0) bcursor[i >> G_SH] = r;
    }
}

// ---------------- edge bucketing (coarse sort by dst>>7) ----------------
// packed word: (d_local << 17) | src   (src < 2^17)
__global__ __launch_bounds__(256) void k_bucket(const int* __restrict__ ei,
                                                int* __restrict__ bcursor,
                                                int* __restrict__ packed, int E, int nb) {
    __shared__ int hcnt[NBK_MAX];
    __shared__ int hoff[NBK_MAX];
    __shared__ int hbase[NBK_MAX];
    __shared__ int hcur[NBK_MAX];
    __shared__ int stage[CHUNK];
    __shared__ unsigned short sbk[CHUNK];
    __shared__ int scan_s[256];
    __shared__ int sh_carry;

    int tid = threadIdx.x;
    int base = blockIdx.x * CHUNK;
    int cnt = E - base;
    if (cnt > CHUNK) cnt = CHUNK;
    for (int t = tid; t < nb; t += 256) { hcnt[t] = 0; hcur[t] = 0; }
    if (tid == 0) sh_carry = 0;
    __syncthreads();

    int mp[CHUNK / 256], mb[CHUNK / 256];
#pragma unroll
    for (int k = 0; k < CHUNK / 256; ++k) {
        int idx = base + k * 256 + tid;
        int p = 0, b = -1;
        if (idx < E) {
            int s = ei[idx];
            int d = ei[E + idx];
            b = d >> G_SH;
            p = ((d & (G_SZ - 1)) << 17) | s;
            atomicAdd(&hcnt[b], 1);
        }
        mp[k] = p; mb[k] = b;
    }
    __syncthreads();

    // exclusive scan of hcnt -> hoff
    for (int s0 = 0; s0 < nb; s0 += 256) {
        int i = s0 + tid;
        int v = (i < nb) ? hcnt[i] : 0;
        scan_s[tid] = v;
        __syncthreads();
        for (int off = 1; off < 256; off <<= 1) {
            int t = (tid >= off) ? scan_s[tid - off] : 0;
            __syncthreads();
            scan_s[tid] += t;
            __syncthreads();
        }
        if (i < nb) hoff[i] = sh_carry + scan_s[tid] - v;
        __syncthreads();
        if (tid == 255) sh_carry += scan_s[255];
        __syncthreads();
    }

    // reserve global space per bucket
    for (int t = tid; t < nb; t += 256)
        if (hcnt[t] > 0) hbase[t] = atomicAdd(&bcursor[t], hcnt[t]);
    __syncthreads();

    // LDS scatter into bucket-ordered staging
#pragma unroll
    for (int k = 0; k < CHUNK / 256; ++k) {
        int b = mb[k];
        if (b >= 0) {
            int slot = hoff[b] + atomicAdd(&hcur[b], 1);
            stage[slot] = mp[k];
            sbk[slot] = (unsigned short)b;
        }
    }
    __syncthreads();

    // coalesced run write-out
    for (int i = tid; i < cnt; i += 256) {
        int b = sbk[i];
        packed[hbase[b] + (i - hoff[b])] = stage[i];
    }
}

// ---------------- per-bucket fine counting sort (in place, strips to src) -------

__global__ __launch_bounds__(256) void k_sortbkt(const int* __restrict__ rowptr,
                                                 const int* __restrict__ counts,
                                                 int* __restrict__ packed, int n) {
    __shared__ int sc[G_SZ];
    __shared__ int loff[G_SZ];
    __shared__ int lcur[G_SZ];
    __shared__ int stage[SORT_CAP];
    __shared__ int sorted_[SORT_CAP];
    __shared__ int sh_L, sh_base;

    int tid = threadIdx.x;
    int d0 = blockIdx.x << G_SH;
    int v = 0;
    if (tid < G_SZ) {
        int d = d0 + tid;
        v = (d < n) ? counts[d] : 0;
        sc[tid] = v;
    }
    if (tid == 0) sh_base = rowptr[d0];
    __syncthreads();
    for (int off = 1; off < G_SZ; off <<= 1) {
        int t = (tid < G_SZ && tid >= off) ? sc[tid - off] : 0;
        __syncthreads();
        if (tid < G_SZ) sc[tid] += t;
        __syncthreads();
    }
    if (tid < G_SZ) {
        loff[tid] = sc[tid] - v;   // exclusive
        lcur[tid] = sc[tid] - v;
    }
    if (tid == G_SZ - 1) sh_L = sc[G_SZ - 1];
    __syncthreads();

    int L = sh_L, base = sh_base;
    for (int i = tid; i < L; i += 256) stage[i] = packed[base + i];
    __syncthreads();
    for (int i = tid; i < L; i += 256) {
        int p = stage[i];
        int dl = p >> 17;
        int pos = atomicAdd(&lcur[dl], 1);
        sorted_[pos] = p & 0x1FFFF;
    }
    __syncthreads();
    for (int i = tid; i < L; i += 256) packed[base + i] = sorted_[i];
}

// ---------------- layer 1 ----------------

// xlp = dinv * (x @ W1); 8 nodes/block, 2 nodes/thread
__global__ __launch_bounds__(256) void k_gemm1(const float* __restrict__ x,
                                               const float* __restrict__ W,
                                               const float* __restrict__ dinv,
                                               float* __restrict__ xlp, int n) {
    __shared__ float sx[8][IN_CH];
    int node0 = blockIdx.x * 8;
    int tid = threadIdx.x;
    {
        int r = tid >> 5, k4 = tid & 31;
        int node = node0 + r;
        float4 v = (node < n) ? ((const float4*)(x + (size_t)node * IN_CH))[k4]
                              : make_float4(0.f, 0.f, 0.f, 0.f);
        ((float4*)sx[r])[k4] = v;
    }
    __syncthreads();
    int r = tid >> 6, j = tid & 63;
    float acc0 = 0.f, acc1 = 0.f;
#pragma unroll 8
    for (int k = 0; k < IN_CH; ++k) {
        float w = W[k * HID + j];
        acc0 += sx[r][k] * w;
        acc1 += sx[r + 4][k] * w;
    }
    int nodeA = node0 + r, nodeB = node0 + r + 4;
    if (nodeA < n) xlp[(size_t)nodeA * HID + j] = dinv[nodeA] * acc0;
    if (nodeB < n) xlp[(size_t)nodeB * HID + j] = dinv[nodeB] * acc1;
}

// h[d] = relu(dd * (sum_s xlp[s] + xlp[d]) + b1). One wave per dst; 8-edge unroll.
__global__ __launch_bounds__(256) void k_agg1(const int* __restrict__ rowptr,
                                              const int* __restrict__ counts,
                                              const int* __restrict__ esrc,
                                              const float* __restrict__ dinv,
                                              const float* __restrict__ xlp,
                                              const float* __restrict__ b,
                                              float* __restrict__ h, int n) {
    int d = blockIdx.x * 4 + (threadIdx.x >> 6);
    int c = threadIdx.x & 63;
    if (d >= n) return;
    int j0 = rowptr[d], j1 = j0 + counts[d];
    float acc = 0.f;
    int j = j0;
    for (; j + 8 <= j1; j += 8) {
        int s0 = esrc[j],     s1 = esrc[j + 1], s2 = esrc[j + 2], s3 = esrc[j + 3];
        int s4 = esrc[j + 4], s5 = esrc[j + 5], s6 = esrc[j + 6], s7 = esrc[j + 7];
        float v0 = xlp[(size_t)s0 * HID + c];
        float v1 = xlp[(size_t)s1 * HID + c];
        float v2 = xlp[(size_t)s2 * HID + c];
        float v3 = xlp[(size_t)s3 * HID + c];
        float v4 = xlp[(size_t)s4 * HID + c];
        float v5 = xlp[(size_t)s5 * HID + c];
        float v6 = xlp[(size_t)s6 * HID + c];
        float v7 = xlp[(size_t)s7 * HID + c];
        acc += ((v0 + v1) + (v2 + v3)) + ((v4 + v5) + (v6 + v7));
    }
    for (; j < j1; ++j) acc += xlp[(size_t)esrc[j] * HID + c];
    float dd = dinv[d];
    float val = dd * (acc + xlp[(size_t)d * HID + c]) + b[c];
    h[(size_t)d * HID + c] = fmaxf(val, 0.f);
}

// ---------------- layer 2 ----------------

// hlp = dinv * (h @ W2); 16 nodes/block
__global__ __launch_bounds__(256) void k_gemm2(const float* __restrict__ h,
                                               const float* __restrict__ W,
                                               const float* __restrict__ dinv,
                                               float* __restrict__ hlp, int n) {
    __shared__ float sW[HID * OUT_CH];
    __shared__ float sh[16][HID];
    int tid = threadIdx.x;
    for (int t = tid; t < HID * OUT_CH; t += 256) sW[t] = W[t];
    int node0 = blockIdx.x * 16;
    for (int t = tid; t < 16 * HID / 4; t += 256) {
        int r = t >> 4, k4 = t & 15;
        int node = node0 + r;
        float4 v = (node < n) ? ((const float4*)(h + (size_t)node * HID))[k4]
                              : make_float4(0.f, 0.f, 0.f, 0.f);
        ((float4*)sh[r])[k4] = v;
    }
    __syncthreads();
    int r = tid >> 4, j = tid & 15;
    int node = node0 + r;
    if (node >= n) return;
    float acc = 0.f;
#pragma unroll
    for (int k = 0; k < HID; ++k)
        acc += sh[r][k] * sW[k * OUT_CH + j];
    hlp[(size_t)node * OUT_CH + j] = dinv[node] * acc;
}

// out[d] = dd * (sum_s hlp[s] + hlp[d]) + b2. One 16-lane group per dst; 4-edge unroll.
__global__ __launch_bounds__(256) void k_agg2(const int* __restrict__ rowptr,
                                              const int* __restrict__ counts,
                                              const int* __restrict__ esrc,
                                              const float* __restrict__ dinv,
                                              const float* __restrict__ hlp,
                                              const float* __restrict__ b,
                                              float* __restrict__ out, int n) {
    int d = blockIdx.x * 16 + (threadIdx.x >> 4);
    int c = threadIdx.x & 15;
    if (d >= n) return;
    int j0 = rowptr[d], j1 = j0 + counts[d];
    float acc = 0.f;
    int j = j0;
    for (; j + 4 <= j1; j += 4) {
        int s0 = esrc[j], s1 = esrc[j + 1], s2 = esrc[j + 2], s3 = esrc[j + 3];
        float v0 = hlp[(size_t)s0 * OUT_CH + c];
        float v1 = hlp[(size_t)s1 * OUT_CH + c];
        float v2 = hlp[(size_t)s2 * OUT_CH + c];
        float v3 = hlp[(size_t)s3 * OUT_CH + c];
        acc += (v0 + v1) + (v2 + v3);
    }
    for (; j < j1; ++j) acc += hlp[(size_t)esrc[j] * OUT_CH + c];
    float dd = dinv[d];
    out[(size_t)d * OUT_CH + c] = dd * (acc + hlp[(size_t)d * OUT_CH + c]) + b[c];
}

extern "C" void kernel_launch(void* const* d_in, const int* in_sizes, int n_in,
                              void* d_out, int out_size, void* d_ws, size_t ws_size,
                              hipStream_t stream) {
    const float* x  = (const float*)d_in[0];
    const int* ei   = (const int*)d_in[1];   // int32 from harness
    const float* W1 = (const float*)d_in[2];
    const float* b1 = (const float*)d_in[3];
    const float* W2 = (const float*)d_in[4];
    const float* b2 = (const float*)d_in[5];
    float* out = (float*)d_out;

    const int n = in_sizes[0] / IN_CH;      // 100000
    const int E = in_sizes[1] / 2;          // 1600000
    const int nblk = (n + 255) / 256;       // 391
    const int nb = (n + G_SZ - 1) >> G_SH;  // 782 buckets

    // workspace (ints): counts n | rowptr n | blk 512 | bcursor 1024 | packed E |
    //                   dinv n | xlp 64n | h 64n   -> 131n + E + 1536 ~= 58.8 MB
    int* counts  = (int*)d_ws;
    int* rowptr  = counts + n;
    int* blk     = rowptr + n;
    int* bcursor = blk + 512;
    int* packed  = bcursor + 1024;
    float* dinv  = (float*)(packed + E);
    float* xlp   = dinv + n;
    float* h     = xlp + (size_t)n * HID;
    float* hlp   = xlp;  // alias: xlp dead after k_agg1

    // degree + rowptr + dinv + bucket cursors
    k_zero_int<<<nblk, 256, 0, stream>>>(counts, n);
    k_count<<<(E + 255) / 256, 256, 0, stream>>>(ei, counts, E);
    k_scan_local<<<nblk, 256, 0, stream>>>(counts, rowptr, blk, dinv, n);
    k_scan_blocks<<<1, 256, 0, stream>>>(blk, nblk);
    k_scan_add<<<nblk, 256, 0, stream>>>(rowptr, blk, bcursor, n);

    // coarse bucket sort + per-bucket fine sort (in place -> CSR-ordered src ids)
    k_bucket<<<(E + CHUNK - 1) / CHUNK, 256, 0, stream>>>(ei, bcursor, packed, E, nb);
    k_sortbkt<<<nb, 256, 0, stream>>>(rowptr, counts, packed, n);

    // layer 1
    k_gemm1<<<(n + 7) / 8, 256, 0, stream>>>(x, W1, dinv, xlp, n);
    k_agg1<<<(n + 3) / 4, 256, 0, stream>>>(rowptr, counts, packed, dinv, xlp, b1, h, n);

    // layer 2
    k_gemm2<<<(n + 15) / 16, 256, 0, stream>>>(h, W2, dinv, hlp, n);
    k_agg2<<<(n + 15) / 16, 256, 0, stream>>>(rowptr, counts, packed, dinv, hlp, b2, out, n);
}